// Round 1
// baseline (62.369 us; speedup 1.0000x reference)
//
#include <hip/hip_runtime.h>

#define BB 4
#define SS 4096
#define EE 128
#define KDD 64
#define NROWS (BB*SS)   // 16384

// ---------------------------------------------------------------------------
// Kernel 1: query = x @ Wq^T (64 cols) and value = x @ Wv^T (128 cols).
// Grid (NROWS/64, 3): colBlock 0 -> query, 1 -> value[:,0:64], 2 -> value[:,64:128]
// Block tile 64 rows x 64 cols, thread tile 4x4, K=128 staged in LDS.
// ---------------------------------------------------------------------------
__global__ __launch_bounds__(256, 2)
void qv_gemm(const float* __restrict__ x, const float* __restrict__ Wq,
             const float* __restrict__ Wv,
             float* __restrict__ query, float* __restrict__ value)
{
    __shared__ float xs[64][132];   // [row][k], pad keeps f4 alignment, 2-way banks
    __shared__ float wst[128][68];  // [k][col]
    const int tid = threadIdx.x;
    const int R0 = blockIdx.x * 64;
    const int cb = blockIdx.y;

    #pragma unroll
    for (int i = 0; i < 8; ++i) {               // stage x tile 64x128
        int f4 = tid + i * 256;
        int row = f4 >> 5, kq = f4 & 31;
        float4 v = *reinterpret_cast<const float4*>(x + (size_t)(R0 + row) * EE + 4 * kq);
        *reinterpret_cast<float4*>(&xs[row][4 * kq]) = v;
    }
    {
        const float* Wbase = (cb == 0) ? Wq : (Wv + (cb == 2 ? 64 * EE : 0));
        #pragma unroll
        for (int i = 0; i < 8; ++i) {           // stage 64 weight rows, transposed
            int f4 = tid + i * 256;
            int c = f4 & 63, kq = f4 >> 6;
            float4 v = *reinterpret_cast<const float4*>(Wbase + (size_t)c * EE + 4 * kq);
            wst[4 * kq + 0][c] = v.x;
            wst[4 * kq + 1][c] = v.y;
            wst[4 * kq + 2][c] = v.z;
            wst[4 * kq + 3][c] = v.w;
        }
    }
    __syncthreads();

    const int ct = tid & 15, rt = tid >> 4;
    const int c0 = 4 * ct, r0 = 4 * rt;
    float acc[4][4] = {};
    #pragma unroll 4
    for (int k0 = 0; k0 < 128; k0 += 4) {
        float4 a[4], bq[4];
        #pragma unroll
        for (int i = 0; i < 4; ++i) a[i] = *reinterpret_cast<const float4*>(&xs[r0 + i][k0]);
        #pragma unroll
        for (int kk = 0; kk < 4; ++kk) bq[kk] = *reinterpret_cast<const float4*>(&wst[k0 + kk][c0]);
        #pragma unroll
        for (int i = 0; i < 4; ++i) {
            const float4 ai = a[i];
            acc[i][0] = fmaf(ai.x, bq[0].x, acc[i][0]);
            acc[i][1] = fmaf(ai.x, bq[0].y, acc[i][1]);
            acc[i][2] = fmaf(ai.x, bq[0].z, acc[i][2]);
            acc[i][3] = fmaf(ai.x, bq[0].w, acc[i][3]);
            acc[i][0] = fmaf(ai.y, bq[1].x, acc[i][0]);
            acc[i][1] = fmaf(ai.y, bq[1].y, acc[i][1]);
            acc[i][2] = fmaf(ai.y, bq[1].z, acc[i][2]);
            acc[i][3] = fmaf(ai.y, bq[1].w, acc[i][3]);
            acc[i][0] = fmaf(ai.z, bq[2].x, acc[i][0]);
            acc[i][1] = fmaf(ai.z, bq[2].y, acc[i][1]);
            acc[i][2] = fmaf(ai.z, bq[2].z, acc[i][2]);
            acc[i][3] = fmaf(ai.z, bq[2].w, acc[i][3]);
            acc[i][0] = fmaf(ai.w, bq[3].x, acc[i][0]);
            acc[i][1] = fmaf(ai.w, bq[3].y, acc[i][1]);
            acc[i][2] = fmaf(ai.w, bq[3].z, acc[i][2]);
            acc[i][3] = fmaf(ai.w, bq[3].w, acc[i][3]);
        }
    }

    if (cb == 0) {
        #pragma unroll
        for (int i = 0; i < 4; ++i) {
            float4 o = make_float4(acc[i][0], acc[i][1], acc[i][2], acc[i][3]);
            *reinterpret_cast<float4*>(query + (size_t)(R0 + r0 + i) * KDD + c0) = o;
        }
    } else {
        const int coff = (cb - 1) * 64 + c0;
        #pragma unroll
        for (int i = 0; i < 4; ++i) {
            float4 o = make_float4(acc[i][0], acc[i][1], acc[i][2], acc[i][3]);
            *reinterpret_cast<float4*>(value + (size_t)(R0 + r0 + i) * EE + coff) = o;
        }
    }
}

// ---------------------------------------------------------------------------
// Kernel 2: key64T[b][k][t] = (t<=k) ? x[b,t,:] . Wk[k,:] : 0   (t,k < 64)
// Grid (B, 8): 8 k-rows per block.
// ---------------------------------------------------------------------------
__global__ __launch_bounds__(256)
void key_gen(const float* __restrict__ x, const float* __restrict__ Wk,
             float* __restrict__ key64T)
{
    __shared__ float xs[64][132];
    __shared__ float wks[8][132];
    const int b = blockIdx.x, kb = blockIdx.y * 8;
    const int tid = threadIdx.x;

    #pragma unroll
    for (int i = 0; i < 8; ++i) {
        int f4 = tid + i * 256;
        int row = f4 >> 5, kq = f4 & 31;
        float4 v = *reinterpret_cast<const float4*>(x + ((size_t)b * SS + row) * EE + 4 * kq);
        *reinterpret_cast<float4*>(&xs[row][4 * kq]) = v;
    }
    if (tid < 256) {
        int row = tid >> 5, kq = tid & 31;
        float4 v = *reinterpret_cast<const float4*>(Wk + (size_t)(kb + row) * EE + 4 * kq);
        *reinterpret_cast<float4*>(&wks[row][4 * kq]) = v;
    }
    __syncthreads();

    const int kl = tid >> 5;        // 0..7
    const int tb = tid & 31;
    const int kg = kb + kl;
    #pragma unroll
    for (int ii = 0; ii < 2; ++ii) {
        const int t = tb + 32 * ii;
        float acc = 0.f;
        #pragma unroll 8
        for (int e4 = 0; e4 < 32; ++e4) {
            float4 a = *reinterpret_cast<const float4*>(&xs[t][4 * e4]);
            float4 w = *reinterpret_cast<const float4*>(&wks[kl][4 * e4]);
            acc = fmaf(a.x, w.x, acc);
            acc = fmaf(a.y, w.y, acc);
            acc = fmaf(a.z, w.z, acc);
            acc = fmaf(a.w, w.w, acc);
        }
        key64T[((size_t)b * 64 + kg) * 64 + t] = (t <= kg) ? acc : 0.f;
    }
}

// ---------------------------------------------------------------------------
// Kernel 3a/3b: Vsum[b][v] = sum_{t=64}^{S-1} value[b][t][v]  (deterministic 2-stage)
// ---------------------------------------------------------------------------
__global__ __launch_bounds__(128)
void vsum1(const float* __restrict__ value, float* __restrict__ vpart)
{
    const int b = blockIdx.x, i = blockIdx.y, tid = threadIdx.x;
    size_t base = ((size_t)b * SS + 64 + (size_t)i * 126) * EE + tid;
    float acc = 0.f;
    for (int r = 0; r < 126; ++r) acc += value[base + (size_t)r * EE];
    vpart[((size_t)b * 32 + i) * EE + tid] = acc;
}

__global__ __launch_bounds__(128)
void vsum2(const float* __restrict__ vpart, float* __restrict__ vsum)
{
    const int b = blockIdx.x, tid = threadIdx.x;
    float acc = 0.f;
    #pragma unroll
    for (int i = 0; i < 32; ++i) acc += vpart[((size_t)b * 32 + i) * EE + tid];
    vsum[(size_t)b * EE + tid] = acc;
}

// ---------------------------------------------------------------------------
// Kernel 4: per (b,s): scores over t<64, softmax incl. (S-64) zeros, output.
// Grid (S/32, B); block = 4 waves, each wave owns 8 rows (4 at a time).
// ---------------------------------------------------------------------------
__device__ __forceinline__ float wave_max64(float v) {
    #pragma unroll
    for (int o = 32; o; o >>= 1) v = fmaxf(v, __shfl_xor(v, o));
    return v;
}
__device__ __forceinline__ float wave_sum64(float v) {
    #pragma unroll
    for (int o = 32; o; o >>= 1) v += __shfl_xor(v, o);
    return v;
}

__global__ __launch_bounds__(256, 2)
void attn_epilogue(const float* __restrict__ query, const float* __restrict__ value,
                   const float* __restrict__ key64T, const float* __restrict__ vsum,
                   float* __restrict__ out)
{
    __shared__ float Ks[64 * 64];    // [k][t]  (pre-masked)
    __shared__ float Vl[64 * 128];   // [t][v]
    __shared__ float qs[32 * 64];    // [r][k]
    __shared__ float vs[128];
    const int tid = threadIdx.x;
    const int b = blockIdx.y;
    const int s0 = blockIdx.x * 32;

    #pragma unroll
    for (int i = 0; i < 4; ++i) {
        int f4 = tid + i * 256;
        *reinterpret_cast<float4*>(&Ks[4 * f4]) =
            *reinterpret_cast<const float4*>(key64T + (size_t)b * 64 * 64 + 4 * f4);
    }
    #pragma unroll
    for (int i = 0; i < 8; ++i) {
        int f4 = tid + i * 256;
        *reinterpret_cast<float4*>(&Vl[4 * f4]) =
            *reinterpret_cast<const float4*>(value + (size_t)b * SS * EE + 4 * f4);
    }
    #pragma unroll
    for (int i = 0; i < 2; ++i) {
        int f4 = tid + i * 256;
        *reinterpret_cast<float4*>(&qs[4 * f4]) =
            *reinterpret_cast<const float4*>(query + ((size_t)b * SS + s0) * KDD + 4 * f4);
    }
    if (tid < 32)
        *reinterpret_cast<float4*>(&vs[4 * tid]) =
            *reinterpret_cast<const float4*>(vsum + (size_t)b * EE + 4 * tid);
    __syncthreads();

    const int wave = tid >> 6, lane = tid & 63;

    #pragma unroll
    for (int rp = 0; rp < 2; ++rp) {
        const int r = wave * 8 + rp * 4;
        float q0 = qs[(r + 0) * 64 + lane];
        float q1 = qs[(r + 1) * 64 + lane];
        float q2 = qs[(r + 2) * 64 + lane];
        float q3 = qs[(r + 3) * 64 + lane];
        float a0 = 0.f, a1 = 0.f, a2 = 0.f, a3 = 0.f;
        #pragma unroll
        for (int k = 0; k < 64; ++k) {
            float kv = Ks[k * 64 + lane];        // zero above diagonal
            a0 = fmaf(__shfl(q0, k), kv, a0);
            a1 = fmaf(__shfl(q1, k), kv, a1);
            a2 = fmaf(__shfl(q2, k), kv, a2);
            a3 = fmaf(__shfl(q3, k), kv, a3);
        }
        // softmax over 4096 columns: 64 real scores + 4032 exact zeros
        float m0 = fmaxf(wave_max64(a0), 0.f);
        float m1 = fmaxf(wave_max64(a1), 0.f);
        float m2 = fmaxf(wave_max64(a2), 0.f);
        float m3 = fmaxf(wave_max64(a3), 0.f);
        float w0 = __expf(a0 - m0), w1 = __expf(a1 - m1);
        float w2 = __expf(a2 - m2), w3 = __expf(a3 - m3);
        float e0 = __expf(-m0), e1 = __expf(-m1), e2 = __expf(-m2), e3 = __expf(-m3);
        float z0 = wave_sum64(w0) + (float)(SS - 64) * e0;
        float z1 = wave_sum64(w1) + (float)(SS - 64) * e1;
        float z2 = wave_sum64(w2) + (float)(SS - 64) * e2;
        float z3 = wave_sum64(w3) + (float)(SS - 64) * e3;

        float o0x = 0.f, o0y = 0.f, o1x = 0.f, o1y = 0.f;
        float o2x = 0.f, o2y = 0.f, o3x = 0.f, o3y = 0.f;
        #pragma unroll
        for (int t = 0; t < 64; ++t) {
            float2 vv = *reinterpret_cast<const float2*>(&Vl[t * 128 + 2 * lane]);
            float w0t = __shfl(w0, t);
            float w1t = __shfl(w1, t);
            float w2t = __shfl(w2, t);
            float w3t = __shfl(w3, t);
            o0x = fmaf(w0t, vv.x, o0x); o0y = fmaf(w0t, vv.y, o0y);
            o1x = fmaf(w1t, vv.x, o1x); o1y = fmaf(w1t, vv.y, o1y);
            o2x = fmaf(w2t, vv.x, o2x); o2y = fmaf(w2t, vv.y, o2y);
            o3x = fmaf(w3t, vv.x, o3x); o3y = fmaf(w3t, vv.y, o3y);
        }
        float2 vsv = *reinterpret_cast<const float2*>(&vs[2 * lane]);
        float iz0 = 1.f / z0, iz1 = 1.f / z1, iz2 = 1.f / z2, iz3 = 1.f / z3;
        float2 r0o = make_float2((o0x + e0 * vsv.x) * iz0, (o0y + e0 * vsv.y) * iz0);
        float2 r1o = make_float2((o1x + e1 * vsv.x) * iz1, (o1y + e1 * vsv.y) * iz1);
        float2 r2o = make_float2((o2x + e2 * vsv.x) * iz2, (o2y + e2 * vsv.y) * iz2);
        float2 r3o = make_float2((o3x + e3 * vsv.x) * iz3, (o3y + e3 * vsv.y) * iz3);
        size_t obase = ((size_t)b * SS + s0 + r) * EE + 2 * lane;
        *reinterpret_cast<float2*>(out + obase + 0 * EE) = r0o;
        *reinterpret_cast<float2*>(out + obase + 1 * EE) = r1o;
        *reinterpret_cast<float2*>(out + obase + 2 * EE) = r2o;
        *reinterpret_cast<float2*>(out + obase + 3 * EE) = r3o;
    }
}

// ---------------------------------------------------------------------------
extern "C" void kernel_launch(void* const* d_in, const int* in_sizes, int n_in,
                              void* d_out, int out_size, void* d_ws, size_t ws_size,
                              hipStream_t stream)
{
    const float* x  = (const float*)d_in[0];
    const float* Wk = (const float*)d_in[1];
    const float* Wq = (const float*)d_in[2];
    const float* Wv = (const float*)d_in[3];
    float* out = (float*)d_out;

    float* ws     = (float*)d_ws;
    float* value  = ws;                                   // NROWS*EE
    float* query  = value + (size_t)NROWS * EE;           // NROWS*KDD
    float* key64T = query + (size_t)NROWS * KDD;          // BB*64*64
    float* vpart  = key64T + (size_t)BB * 64 * 64;        // BB*32*EE
    float* vsum   = vpart + (size_t)BB * 32 * EE;         // BB*EE

    qv_gemm<<<dim3(NROWS / 64, 3), 256, 0, stream>>>(x, Wq, Wv, query, value);
    key_gen<<<dim3(BB, 8), 256, 0, stream>>>(x, Wk, key64T);
    vsum1<<<dim3(BB, 32), 128, 0, stream>>>(value, vpart);
    vsum2<<<BB, 128, 0, stream>>>(vpart, vsum);
    attn_epilogue<<<dim3(SS / 32, BB), 256, 0, stream>>>(query, value, key64T, vsum, out);
}

// Round 2
// 34.960 us; speedup vs baseline: 1.7840x; 1.7840x over previous
//
#include <hip/hip_runtime.h>

#define BB 4
#define SS 4096
#define EE 128
#define KDD 64
#define NROWS (BB*SS)   // 16384

// ---------------------------------------------------------------------------
// Kernel A: uniform 64x64 GEMM blocks, K=128, thread tile 4x4.
//  blocks [0,256):   query[R0..R0+63][0:64] = x @ Wq^T; also xpart column sums
//                    (excluding rows s<64 => first block of each batch writes 0)
//  blocks [256,268): idx=bx-256, b=idx/3, role=idx%3 on x[b,0:64]:
//    role 0: value64[b][t][0:64]   = x64 @ Wv[0:64]^T
//    role 1: value64[b][t][64:128] = x64 @ Wv[64:128]^T
//    role 2: key64T[b][k][t] = (t<=k) ? x64[t].Wk[k] : 0
// ---------------------------------------------------------------------------
__global__ __launch_bounds__(256, 2)
void fused_a(const float* __restrict__ x, const float* __restrict__ Wq,
             const float* __restrict__ Wk, const float* __restrict__ Wv,
             float* __restrict__ query, float* __restrict__ value64,
             float* __restrict__ key64T, float* __restrict__ xpart)
{
    __shared__ float xs[64][132];
    __shared__ float wst[128][68];
    const int tid = threadIdx.x;
    const int bx = blockIdx.x;

    int xrow0, role, b;
    const float* Wbase;
    if (bx < 256) {
        xrow0 = bx * 64; Wbase = Wq; role = -1; b = bx >> 6;
    } else {
        const int idx = bx - 256;
        b = idx / 3; role = idx % 3;
        xrow0 = b * SS;
        Wbase = (role == 0) ? Wv : (role == 1) ? (Wv + 64 * EE) : Wk;
    }

    #pragma unroll
    for (int i = 0; i < 8; ++i) {               // stage 64x128 x tile
        int f4 = tid + i * 256;
        int row = f4 >> 5, kq = f4 & 31;
        float4 v = *reinterpret_cast<const float4*>(x + (size_t)(xrow0 + row) * EE + 4 * kq);
        *reinterpret_cast<float4*>(&xs[row][4 * kq]) = v;
    }
    #pragma unroll
    for (int i = 0; i < 8; ++i) {               // stage 64 weight rows transposed
        int f4 = tid + i * 256;
        int c = f4 & 63, kq = f4 >> 6;
        float4 v = *reinterpret_cast<const float4*>(Wbase + (size_t)c * EE + 4 * kq);
        wst[4 * kq + 0][c] = v.x;
        wst[4 * kq + 1][c] = v.y;
        wst[4 * kq + 2][c] = v.z;
        wst[4 * kq + 3][c] = v.w;
    }
    __syncthreads();

    const int ct = tid & 15, rt = tid >> 4;
    const int c0 = 4 * ct, r0 = 4 * rt;
    float acc[4][4] = {};
    #pragma unroll 4
    for (int k0 = 0; k0 < 128; k0 += 4) {
        float4 a[4], bq[4];
        #pragma unroll
        for (int i = 0; i < 4; ++i) a[i] = *reinterpret_cast<const float4*>(&xs[r0 + i][k0]);
        #pragma unroll
        for (int kk = 0; kk < 4; ++kk) bq[kk] = *reinterpret_cast<const float4*>(&wst[k0 + kk][c0]);
        #pragma unroll
        for (int i = 0; i < 4; ++i) {
            const float4 ai = a[i];
            acc[i][0] = fmaf(ai.x, bq[0].x, acc[i][0]);
            acc[i][1] = fmaf(ai.x, bq[0].y, acc[i][1]);
            acc[i][2] = fmaf(ai.x, bq[0].z, acc[i][2]);
            acc[i][3] = fmaf(ai.x, bq[0].w, acc[i][3]);
            acc[i][0] = fmaf(ai.y, bq[1].x, acc[i][0]);
            acc[i][1] = fmaf(ai.y, bq[1].y, acc[i][1]);
            acc[i][2] = fmaf(ai.y, bq[1].z, acc[i][2]);
            acc[i][3] = fmaf(ai.y, bq[1].w, acc[i][3]);
            acc[i][0] = fmaf(ai.z, bq[2].x, acc[i][0]);
            acc[i][1] = fmaf(ai.z, bq[2].y, acc[i][1]);
            acc[i][2] = fmaf(ai.z, bq[2].z, acc[i][2]);
            acc[i][3] = fmaf(ai.z, bq[2].w, acc[i][3]);
            acc[i][0] = fmaf(ai.w, bq[3].x, acc[i][0]);
            acc[i][1] = fmaf(ai.w, bq[3].y, acc[i][1]);
            acc[i][2] = fmaf(ai.w, bq[3].z, acc[i][2]);
            acc[i][3] = fmaf(ai.w, bq[3].w, acc[i][3]);
        }
    }

    if (role < 0) {
        #pragma unroll
        for (int i = 0; i < 4; ++i) {
            float4 o = make_float4(acc[i][0], acc[i][1], acc[i][2], acc[i][3]);
            *reinterpret_cast<float4*>(query + (size_t)(xrow0 + r0 + i) * KDD + c0) = o;
        }
        if (tid < 128) {            // x column partial sums for Vsum
            float s = 0.f;
            if ((bx & 63) != 0) {   // first block of batch covers s<64: excluded
                #pragma unroll 8
                for (int r = 0; r < 64; ++r) s += xs[r][tid];
            }
            xpart[(size_t)bx * 128 + tid] = s;
        }
    } else if (role <= 1) {
        const int voff = role * 64 + c0;
        #pragma unroll
        for (int i = 0; i < 4; ++i) {
            float4 o = make_float4(acc[i][0], acc[i][1], acc[i][2], acc[i][3]);
            *reinterpret_cast<float4*>(value64 + ((size_t)b * 64 + r0 + i) * EE + voff) = o;
        }
    } else {
        #pragma unroll
        for (int i = 0; i < 4; ++i)
            #pragma unroll
            for (int j = 0; j < 4; ++j) {
                const int t = r0 + i, k = c0 + j;
                key64T[((size_t)b * 64 + k) * 64 + t] = (t <= k) ? acc[i][j] : 0.f;
            }
    }
}

// ---------------------------------------------------------------------------
// Kernel B: xsum[b] = sum over 64 block-partials; vsum[b][v] = xsum . Wv[v]
// ---------------------------------------------------------------------------
__global__ __launch_bounds__(128)
void vsum_b(const float* __restrict__ xpart, const float* __restrict__ Wv,
            float* __restrict__ vsum)
{
    __shared__ float xsum[128];
    const int b = blockIdx.x, tid = threadIdx.x;
    float s = 0.f;
    #pragma unroll 8
    for (int i = 0; i < 64; ++i) s += xpart[(((size_t)b * 64 + i) << 7) + tid];
    xsum[tid] = s;
    __syncthreads();
    float acc = 0.f;
    #pragma unroll 8
    for (int e = 0; e < 128; e += 4) {
        float4 w = *reinterpret_cast<const float4*>(Wv + (size_t)tid * EE + e);
        acc = fmaf(xsum[e + 0], w.x, acc);
        acc = fmaf(xsum[e + 1], w.y, acc);
        acc = fmaf(xsum[e + 2], w.z, acc);
        acc = fmaf(xsum[e + 3], w.w, acc);
    }
    vsum[(size_t)b * EE + tid] = acc;
}

// ---------------------------------------------------------------------------
// Kernel C: per (b,s): 64 scores, softmax incl. (S-64) zero columns, PV + Vsum.
// Grid (S/32, B); 4 waves, each owns 8 rows (two row-quads).
// q and w broadcasts come from LDS (uniform ds_read_b128), no shuffles in loops.
// ---------------------------------------------------------------------------
__device__ __forceinline__ float wave_max64(float v) {
    #pragma unroll
    for (int o = 32; o; o >>= 1) v = fmaxf(v, __shfl_xor(v, o));
    return v;
}
__device__ __forceinline__ float wave_sum64(float v) {
    #pragma unroll
    for (int o = 32; o; o >>= 1) v += __shfl_xor(v, o);
    return v;
}

__global__ __launch_bounds__(256, 2)
void attn_epilogue(const float* __restrict__ query, const float* __restrict__ value64,
                   const float* __restrict__ key64T, const float* __restrict__ vsum,
                   float* __restrict__ out)
{
    __shared__ float Ks[64 * 64];    // [k][t] pre-masked
    __shared__ float Vl[64 * 128];   // [t][v]
    __shared__ float qs[32 * 64];    // [r][k]
    __shared__ float wsm[32 * 64];   // [r][t] softmax numerators
    __shared__ float vs[128];
    const int tid = threadIdx.x;
    const int b = blockIdx.y;
    const int s0 = blockIdx.x * 32;

    #pragma unroll
    for (int i = 0; i < 4; ++i) {
        int f4 = tid + i * 256;
        *reinterpret_cast<float4*>(&Ks[4 * f4]) =
            *reinterpret_cast<const float4*>(key64T + (size_t)b * 64 * 64 + 4 * f4);
    }
    #pragma unroll
    for (int i = 0; i < 8; ++i) {
        int f4 = tid + i * 256;
        *reinterpret_cast<float4*>(&Vl[4 * f4]) =
            *reinterpret_cast<const float4*>(value64 + (size_t)b * 64 * EE + 4 * f4);
    }
    #pragma unroll
    for (int i = 0; i < 2; ++i) {
        int f4 = tid + i * 256;
        *reinterpret_cast<float4*>(&qs[4 * f4]) =
            *reinterpret_cast<const float4*>(query + ((size_t)b * SS + s0) * KDD + 4 * f4);
    }
    if (tid < 32)
        *reinterpret_cast<float4*>(&vs[4 * tid]) =
            *reinterpret_cast<const float4*>(vsum + (size_t)b * EE + 4 * tid);
    __syncthreads();

    const int wave = tid >> 6, lane = tid & 63;

    #pragma unroll
    for (int rp = 0; rp < 2; ++rp) {
        const int r = wave * 8 + rp * 4;
        float a0 = 0.f, a1 = 0.f, a2 = 0.f, a3 = 0.f;
        #pragma unroll
        for (int k0 = 0; k0 < 64; k0 += 4) {
            float4 q0v = *reinterpret_cast<const float4*>(&qs[(r + 0) * 64 + k0]);
            float4 q1v = *reinterpret_cast<const float4*>(&qs[(r + 1) * 64 + k0]);
            float4 q2v = *reinterpret_cast<const float4*>(&qs[(r + 2) * 64 + k0]);
            float4 q3v = *reinterpret_cast<const float4*>(&qs[(r + 3) * 64 + k0]);
            float kv0 = Ks[(k0 + 0) * 64 + lane];
            float kv1 = Ks[(k0 + 1) * 64 + lane];
            float kv2 = Ks[(k0 + 2) * 64 + lane];
            float kv3 = Ks[(k0 + 3) * 64 + lane];
            a0 = fmaf(q0v.x, kv0, a0); a0 = fmaf(q0v.y, kv1, a0);
            a0 = fmaf(q0v.z, kv2, a0); a0 = fmaf(q0v.w, kv3, a0);
            a1 = fmaf(q1v.x, kv0, a1); a1 = fmaf(q1v.y, kv1, a1);
            a1 = fmaf(q1v.z, kv2, a1); a1 = fmaf(q1v.w, kv3, a1);
            a2 = fmaf(q2v.x, kv0, a2); a2 = fmaf(q2v.y, kv1, a2);
            a2 = fmaf(q2v.z, kv2, a2); a2 = fmaf(q2v.w, kv3, a2);
            a3 = fmaf(q3v.x, kv0, a3); a3 = fmaf(q3v.y, kv1, a3);
            a3 = fmaf(q3v.z, kv2, a3); a3 = fmaf(q3v.w, kv3, a3);
        }
        // softmax over 4096 cols: 64 real + 4032 exact zeros
        float m0 = fmaxf(wave_max64(a0), 0.f);
        float m1 = fmaxf(wave_max64(a1), 0.f);
        float m2 = fmaxf(wave_max64(a2), 0.f);
        float m3 = fmaxf(wave_max64(a3), 0.f);
        float w0 = __expf(a0 - m0), w1 = __expf(a1 - m1);
        float w2 = __expf(a2 - m2), w3 = __expf(a3 - m3);
        float e0 = __expf(-m0), e1 = __expf(-m1), e2 = __expf(-m2), e3 = __expf(-m3);
        float z0 = wave_sum64(w0) + (float)(SS - 64) * e0;
        float z1 = wave_sum64(w1) + (float)(SS - 64) * e1;
        float z2 = wave_sum64(w2) + (float)(SS - 64) * e2;
        float z3 = wave_sum64(w3) + (float)(SS - 64) * e3;
        wsm[(r + 0) * 64 + lane] = w0;
        wsm[(r + 1) * 64 + lane] = w1;
        wsm[(r + 2) * 64 + lane] = w2;
        wsm[(r + 3) * 64 + lane] = w3;

        float o0x = 0.f, o0y = 0.f, o1x = 0.f, o1y = 0.f;
        float o2x = 0.f, o2y = 0.f, o3x = 0.f, o3y = 0.f;
        #pragma unroll
        for (int t0 = 0; t0 < 64; t0 += 4) {
            float4 w0v = *reinterpret_cast<const float4*>(&wsm[(r + 0) * 64 + t0]);
            float4 w1v = *reinterpret_cast<const float4*>(&wsm[(r + 1) * 64 + t0]);
            float4 w2v = *reinterpret_cast<const float4*>(&wsm[(r + 2) * 64 + t0]);
            float4 w3v = *reinterpret_cast<const float4*>(&wsm[(r + 3) * 64 + t0]);
            float2 v0 = *reinterpret_cast<const float2*>(&Vl[(t0 + 0) * 128 + 2 * lane]);
            float2 v1 = *reinterpret_cast<const float2*>(&Vl[(t0 + 1) * 128 + 2 * lane]);
            float2 v2 = *reinterpret_cast<const float2*>(&Vl[(t0 + 2) * 128 + 2 * lane]);
            float2 v3 = *reinterpret_cast<const float2*>(&Vl[(t0 + 3) * 128 + 2 * lane]);
            o0x = fmaf(w0v.x, v0.x, o0x); o0y = fmaf(w0v.x, v0.y, o0y);
            o0x = fmaf(w0v.y, v1.x, o0x); o0y = fmaf(w0v.y, v1.y, o0y);
            o0x = fmaf(w0v.z, v2.x, o0x); o0y = fmaf(w0v.z, v2.y, o0y);
            o0x = fmaf(w0v.w, v3.x, o0x); o0y = fmaf(w0v.w, v3.y, o0y);
            o1x = fmaf(w1v.x, v0.x, o1x); o1y = fmaf(w1v.x, v0.y, o1y);
            o1x = fmaf(w1v.y, v1.x, o1x); o1y = fmaf(w1v.y, v1.y, o1y);
            o1x = fmaf(w1v.z, v2.x, o1x); o1y = fmaf(w1v.z, v2.y, o1y);
            o1x = fmaf(w1v.w, v3.x, o1x); o1y = fmaf(w1v.w, v3.y, o1y);
            o2x = fmaf(w2v.x, v0.x, o2x); o2y = fmaf(w2v.x, v0.y, o2y);
            o2x = fmaf(w2v.y, v1.x, o2x); o2y = fmaf(w2v.y, v1.y, o2y);
            o2x = fmaf(w2v.z, v2.x, o2x); o2y = fmaf(w2v.z, v2.y, o2y);
            o2x = fmaf(w2v.w, v3.x, o2x); o2y = fmaf(w2v.w, v3.y, o2y);
            o3x = fmaf(w3v.x, v0.x, o3x); o3y = fmaf(w3v.x, v0.y, o3y);
            o3x = fmaf(w3v.y, v1.x, o3x); o3y = fmaf(w3v.y, v1.y, o3y);
            o3x = fmaf(w3v.z, v2.x, o3x); o3y = fmaf(w3v.z, v2.y, o3y);
            o3x = fmaf(w3v.w, v3.x, o3x); o3y = fmaf(w3v.w, v3.y, o3y);
        }
        float2 vsv = *reinterpret_cast<const float2*>(&vs[2 * lane]);
        float iz0 = 1.f / z0, iz1 = 1.f / z1, iz2 = 1.f / z2, iz3 = 1.f / z3;
        float2 r0o = make_float2((o0x + e0 * vsv.x) * iz0, (o0y + e0 * vsv.y) * iz0);
        float2 r1o = make_float2((o1x + e1 * vsv.x) * iz1, (o1y + e1 * vsv.y) * iz1);
        float2 r2o = make_float2((o2x + e2 * vsv.x) * iz2, (o2y + e2 * vsv.y) * iz2);
        float2 r3o = make_float2((o3x + e3 * vsv.x) * iz3, (o3y + e3 * vsv.y) * iz3);
        size_t obase = ((size_t)b * SS + s0 + r) * EE + 2 * lane;
        *reinterpret_cast<float2*>(out + obase + 0 * EE) = r0o;
        *reinterpret_cast<float2*>(out + obase + 1 * EE) = r1o;
        *reinterpret_cast<float2*>(out + obase + 2 * EE) = r2o;
        *reinterpret_cast<float2*>(out + obase + 3 * EE) = r3o;
    }
}

// ---------------------------------------------------------------------------
extern "C" void kernel_launch(void* const* d_in, const int* in_sizes, int n_in,
                              void* d_out, int out_size, void* d_ws, size_t ws_size,
                              hipStream_t stream)
{
    const float* x  = (const float*)d_in[0];
    const float* Wk = (const float*)d_in[1];
    const float* Wq = (const float*)d_in[2];
    const float* Wv = (const float*)d_in[3];
    float* out = (float*)d_out;

    float* ws      = (float*)d_ws;
    float* query   = ws;                                    // NROWS*KDD
    float* value64 = query + (size_t)NROWS * KDD;           // BB*64*EE
    float* key64T  = value64 + (size_t)BB * 64 * EE;        // BB*64*64
    float* xpart   = key64T + (size_t)BB * 64 * 64;         // 256*128
    float* vsum    = xpart + (size_t)256 * 128;             // BB*EE

    fused_a<<<268, 256, 0, stream>>>(x, Wq, Wk, Wv, query, value64, key64T, xpart);
    vsum_b<<<BB, 128, 0, stream>>>(xpart, Wv, vsum);
    attn_epilogue<<<dim3(SS / 32, BB), 256, 0, stream>>>(query, value64, key64T, vsum, out);
}